// Round 12
// baseline (577.796 us; speedup 1.0000x reference)
//
#include <hip/hip_runtime.h>
#include <stdint.h>

#define D 128
#define TN 160000
#define NSUB 3200
#define GG 64
#define NL 4

typedef __bf16 bf16x8 __attribute__((ext_vector_type(8)));
typedef float f32x4 __attribute__((ext_vector_type(4)));
typedef unsigned int u32x4 __attribute__((ext_vector_type(4)));

__device__ __forceinline__ unsigned short f2bf(float v) {
    union { float f; uint32_t u; } c; c.f = v;
    uint32_t r = c.u + 0x7fffu + ((c.u >> 16) & 1u);
    return (unsigned short)(r >> 16);
}
__device__ __forceinline__ float bf2f(unsigned short h) {
    union { float f; uint32_t u; } c; c.u = ((uint32_t)h) << 16;
    return c.f;
}

__device__ __forceinline__ void gload16(const void* g, void* l) {
    __builtin_amdgcn_global_load_lds(
        (const __attribute__((address_space(1))) unsigned int*)g,
        (__attribute__((address_space(3))) unsigned int*)l, 16, 0, 0);
}

// ---------------------------------------------------------------------------
// Fused GraphConv, aggregation-as-MFMA. Block = 2 units (100 rows) x 256 cols.
// Grid 1632: blocks <1600 = node-conv (A3), >=1600 = subgraph-conv (XS).
// LDS (47616 B -> 3 blocks/CU):
//   phase 1-2: A [100][128] sh swz @0..25600; B wave-private SINGLE buffer
//              4KB/wave @25600+wv*4096 (..41984)
//   phase 3-4: YnT [128][136] sh @0..34816 (over A+B); Adj [2][50][64] sh swz
//              @34816..47616 (over dead B), staged by waves 0,1 in phase 3.
// B single-buffer protocol (wave-private => intra-wave ordering only):
//   vmcnt(0) [stage t done] -> ds_read frags -> lgkmcnt(0)+sched_barrier
//   [reads landed] -> issue stage t+1 into same buffer -> MFMAs.
// Main GEMM: 2-term precision y = x_hi*(Whi+Wlo), m-frags {0,16,32,34}/unit.
// Aggregation: agg = Adj x YnT via MFMA (C-frag layout == Yr frag layout),
// H = Yr+agg+bias in regs -> bf16 store; BN stats -> 64-way replicas.
// ---------------------------------------------------------------------------
__global__ __launch_bounds__(256, 3)
void gconv_kernel(const unsigned short* __restrict__ A3,
                  const unsigned short* __restrict__ XS,
                  const unsigned short* __restrict__ Wt1,
                  const unsigned short* __restrict__ Wt2,
                  const float* __restrict__ bias1,
                  const float* __restrict__ bias2,
                  const unsigned short* __restrict__ AdjS,
                  const unsigned short* __restrict__ AdjO,
                  unsigned short* __restrict__ H1,
                  unsigned short* __restrict__ H2,
                  float* __restrict__ stats)
{
    __shared__ __align__(16) char lds[47616];

    const int tid = threadIdx.x;
    const int blk = blockIdx.x;
    const bool big = blk < 1600;
    const int lb = big ? blk : blk - 1600;
    const unsigned short* Asrc = big ? A3 : XS;
    const unsigned short* Wt = big ? Wt1 : Wt2;
    const float* bias = big ? bias1 : bias2;
    const unsigned short* AdjG = (big ? AdjS : AdjO) + (size_t)lb * 6400;
    unsigned short* H = big ? H1 : H2;
    float* rep = stats + (big ? 0 : 16384) + (size_t)(lb & 63) * 256;
    const int rowbase = lb * 100;

    const int lane = tid & 63, wv = tid >> 6;
    const int p = lane & 15, q = lane >> 4;
    const int wn0 = wv * 64;

    // ---- phase 1: stage A (1600 granules, swz) + B tile 0 ----
#pragma unroll
    for (int i = 0; i < 6; ++i) {
        const int c = i * 256 + tid;
        const int r = c >> 4, g = c & 15;
        gload16(Asrc + (size_t)(rowbase + r) * 128 + ((g ^ (r & 7)) << 3),
                lds + ((i * 256 + (wv << 6)) << 4));
    }
    if (wv == 0) {
        const int c = 1536 + lane;
        const int r = c >> 4, g = c & 15;
        gload16(Asrc + (size_t)(rowbase + r) * 128 + ((g ^ (r & 7)) << 3),
                lds + (1536 << 4));
    }
    {
        char* dst = lds + 25600 + (wv << 12);
#pragma unroll
        for (int j = 0; j < 4; ++j)
            gload16(Wt + (size_t)wn0 * 32 + (size_t)(j * 64 + lane) * 8,
                    dst + (j << 10));
    }

    f32x4 acc[8][4];
#pragma unroll
    for (int i = 0; i < 8; ++i)
#pragma unroll
        for (int j = 0; j < 4; ++j) acc[i][j] = (f32x4){0.f, 0.f, 0.f, 0.f};

    __syncthreads();   // barrier 1: A + B0 ready

    // ---- phase 2: K-loop, 8 tiles, wave-private single-buffer B ----
    static const int FR[8] = {0, 16, 32, 34, 50, 66, 82, 84};
    const unsigned short* Ash = (const unsigned short*)lds;
    const unsigned short* Bw = (const unsigned short*)(lds + 25600 + (wv << 12));
#pragma unroll
    for (int t = 0; t < 8; ++t) {
        if (t > 0) asm volatile("s_waitcnt vmcnt(0)" ::: "memory");
        bf16x8 bfr[4];
#pragma unroll
        for (int ni = 0; ni < 4; ++ni) {
            u32x4 raw = *(const u32x4*)&Bw[(ni * 16 + p) * 32 + q * 8];
            bfr[ni] = __builtin_bit_cast(bf16x8, raw);
        }
        if (t < 7) {
            asm volatile("s_waitcnt lgkmcnt(0)" ::: "memory");
            __builtin_amdgcn_sched_barrier(0);
            char* dst = lds + 25600 + (wv << 12);
#pragma unroll
            for (int j = 0; j < 4; ++j)
                gload16(Wt + ((size_t)(t + 1) << 13) + (size_t)wn0 * 32 +
                            (size_t)(j * 64 + lane) * 8,
                        dst + (j << 10));
        }
        const int gb = (t & 3) * 4 + q;
        __builtin_amdgcn_s_setprio(1);
#pragma unroll
        for (int mi = 0; mi < 8; ++mi) {
            const int rr = FR[mi] + p;
            u32x4 raw = *(const u32x4*)&Ash[rr * 128 + ((gb ^ (rr & 7)) << 3)];
            bf16x8 afr = __builtin_bit_cast(bf16x8, raw);
#pragma unroll
            for (int ni = 0; ni < 4; ++ni)
                acc[mi][ni] = __builtin_amdgcn_mfma_f32_16x16x32_bf16(afr, bfr[ni], acc[mi][ni], 0, 0, 0);
        }
        __builtin_amdgcn_s_setprio(0);
    }

    __syncthreads();   // barrier 2: all A/B reads done; region reusable

    // ---- phase 3: waves 2,3 dump YnT (bf16, transposed);
    //               waves 0,1 zero-pad YnT + stage Adj into dead-B space ----
    static const int F4[4] = {0, 16, 32, 34};
    unsigned short* YnT = (unsigned short*)lds;
    if (wv >= 2) {
        const int cb = (wv - 2) * 64;
#pragma unroll
        for (int u = 0; u < 2; ++u)
#pragma unroll
            for (int fi = 0; fi < 4; ++fi) {
#pragma unroll
                for (int rp = 0; rp < 4; rp += 2) {
                    if (fi == 3 && (q * 4 + rp) < 14) continue;
                    const int jl = F4[fi] + q * 4 + rp;
#pragma unroll
                    for (int ni = 0; ni < 4; ++ni) {
                        const int c = cb + ni * 16 + p;
                        const uint32_t v =
                            (uint32_t)f2bf(acc[u * 4 + fi][ni][rp]) |
                            ((uint32_t)f2bf(acc[u * 4 + fi][ni][rp + 1]) << 16);
                        *(uint32_t*)&YnT[c * 136 + u * 64 + jl] = v;
                    }
                }
            }
    } else {
        // stage Adj: 800 granules of 16B by 128 threads (waves 0,1)
#pragma unroll
        for (int i = 0; i < 6; ++i) {
            const int c = i * 128 + (wv << 6);
            gload16(AdjG + (size_t)(c + lane) * 8, lds + 34816 + (c << 4));
        }
        if (wv == 0 && lane < 32)
            gload16(AdjG + (size_t)(768 + lane) * 8, lds + 34816 + (768 << 4));
        // zero-pad YnT rows 50..63 of both unit halves
        const int c = wv * 64 + lane;
#pragma unroll
        for (int u = 0; u < 2; ++u)
#pragma unroll
            for (int k = 0; k < 7; ++k)
                *(uint32_t*)&YnT[c * 136 + u * 64 + 50 + k * 2] = 0;
    }
    __syncthreads();   // barrier 3: YnT + Adj ready (drains vmcnt)

    // ---- phase 4: waves 0,1: agg = Adj x YnT (MFMA), H = Yr+agg+bias ----
    if (wv < 2) {
        const int cb = wv * 64;
        const unsigned short* AdjL = (const unsigned short*)(lds + 34816);
        float sm[4] = {0.f, 0.f, 0.f, 0.f}, sq[4] = {0.f, 0.f, 0.f, 0.f};
        float bv[4];
#pragma unroll
        for (int ni = 0; ni < 4; ++ni) bv[ni] = bias[cb + ni * 16 + p];
#pragma unroll
        for (int u = 0; u < 2; ++u) {
            f32x4 aacc[4][4];
#pragma unroll
            for (int i = 0; i < 4; ++i)
#pragma unroll
                for (int j = 0; j < 4; ++j) aacc[i][j] = (f32x4){0.f, 0.f, 0.f, 0.f};
#pragma unroll
            for (int ks = 0; ks < 2; ++ks) {
                bf16x8 afr[4], bfr2[4];
#pragma unroll
                for (int fi = 0; fi < 4; ++fi) {
                    const int m = F4[fi] + p;
                    const int gi = ks * 4 + q;
                    u32x4 raw = *(const u32x4*)&AdjL[(u * 50 + m) * 64 + ((gi ^ (m & 7)) << 3)];
                    afr[fi] = __builtin_bit_cast(bf16x8, raw);
                }
#pragma unroll
                for (int ni = 0; ni < 4; ++ni) {
                    u32x4 raw = *(const u32x4*)&YnT[(cb + ni * 16 + p) * 136 + u * 64 + ks * 32 + q * 8];
                    bfr2[ni] = __builtin_bit_cast(bf16x8, raw);
                }
#pragma unroll
                for (int fi = 0; fi < 4; ++fi)
#pragma unroll
                    for (int ni = 0; ni < 4; ++ni)
                        aacc[fi][ni] = __builtin_amdgcn_mfma_f32_16x16x32_bf16(afr[fi], bfr2[ni], aacc[fi][ni], 0, 0, 0);
            }
#pragma unroll
            for (int fi = 0; fi < 4; ++fi)
#pragma unroll
                for (int r = 0; r < 4; ++r) {
                    if (fi == 3 && (q * 4 + r) < 14) continue;
                    const int row = u * 50 + F4[fi] + q * 4 + r;
#pragma unroll
                    for (int ni = 0; ni < 4; ++ni) {
                        const int cc = cb + ni * 16 + p;
                        const float h = acc[u * 4 + fi][ni][r] + aacc[fi][ni][r] + bv[ni];
                        H[(size_t)(rowbase + row) * 128 + cc] = f2bf(h);
                        sm[ni] += h; sq[ni] += h * h;
                    }
                }
        }
#pragma unroll
        for (int ni = 0; ni < 4; ++ni) {
            atomicAdd(&rep[cb + ni * 16 + p], sm[ni]);
            atomicAdd(&rep[128 + cb + ni * 16 + p], sq[ni]);
        }
    }
}

// ---------------------------------------------------------------------------
// adj_build: one block per unit. Dense [50][64] multiplicity matrix in LDS,
// written out bf16 ([50][64] = 3200 shorts per unit, contiguous across units)
// with the gconv granule swizzle pre-applied.
// ---------------------------------------------------------------------------
__global__ void adj_build(const int* __restrict__ src, const int* __restrict__ dst,
                          unsigned short* __restrict__ AdjG)
{
    __shared__ int cnt[3200];
    const int u = blockIdx.x, t = threadIdx.x;
    for (int i = t; i < 3200; i += 256) cnt[i] = 0;
    __syncthreads();
    for (int e = t; e < 400; e += 256) {
        const int d = dst[u * 400 + e] - u * 50;
        const int s = src[u * 400 + e] - u * 50;
        atomicAdd(&cnt[d * 64 + s], 1);
    }
    __syncthreads();
    for (int i = t; i < 3200; i += 256) {
        const int m = i >> 6, j = i & 63;
        const float v = (float)cnt[i];
        const int pos = m * 64 + ((((j >> 3) ^ (m & 7)) << 3) | (j & 7));
        AdjG[(size_t)u * 3200 + pos] = f2bf(v);
    }
}

// ---------------------------------------------------------------------------
// fuse (BN1+BN2[node_idx]+relu) + bf16 -> A3 (hi only), subgraph-mean -> XS.
// ---------------------------------------------------------------------------
template <bool FUSE>
__global__ __launch_bounds__(256)
void fusexsum_kernel(const void* __restrict__ HPv,
                     const unsigned short* __restrict__ H2,
                     const float* __restrict__ prm,
                     unsigned short* __restrict__ A3,
                     unsigned short* __restrict__ XS)
{
    __shared__ float red[256];
    const unsigned short* HPb = (const unsigned short*)HPv;
    const float* HPf = (const float*)HPv;
    const int blk = blockIdx.x;          // g*50 + n
    const int g = blk / 50, n = blk - g * 50;
    const int tid = threadIdx.x;
    const int c = tid & 127, sh = tid >> 7;
    float a1 = 0.f, c1 = 0.f, hh = 0.f;
    if (FUSE) {
        a1 = prm[c]; c1 = prm[128 + c];
        const float a2 = prm[256 + c], c2 = prm[384 + c];
        hh = a2 * bf2f(H2[(size_t)blk * 128 + c]) + c2;
    }
    float accum = 0.f;
    const int s0 = sh * 25;
    for (int s = s0; s < s0 + 25; ++s) {
        const size_t row = (size_t)g * 2500 + s * 50 + n;
        float v = FUSE ? bf2f(HPb[row * 128 + c]) : HPf[row * 128 + c];
        if (FUSE) v = fmaxf(0.f, a1 * v + c1 + hh);
        A3[row * 128 + c] = f2bf(v);
        accum += v;
    }
    red[tid] = accum;
    __syncthreads();
    if (tid < 128) {
        const float xv = (red[tid] + red[tid + 128]) * 0.02f;
        XS[(size_t)blk * 128 + c] = f2bf(xv);
    }
}

// build W3T: 8 matrices x 8 tiles x [256 n][32 k] bf16; tiles 0-3 = hi(W),
// tiles 4-7 = lo(W) k-slices.
__global__ void w3t_kernel(const float* __restrict__ Wr, const float* __restrict__ Wn,
                           const float* __restrict__ Wsr, const float* __restrict__ Wsn,
                           unsigned short* __restrict__ W3T)
{
    const int idx = blockIdx.x * 256 + threadIdx.x;  // 8*65536
    const int m = idx >> 16;
    const int r = idx & 65535;
    const int bt = r >> 13;
    const int rr = r & 8191;
    const int n = rr >> 5, kloc = rr & 31;
    const int kg = (bt & 3) * 32 + kloc;
    const float* Wa = (m < 4) ? Wr + (size_t)m * 16384 : Wsr + (size_t)(m - 4) * 16384;
    const float* Wb = (m < 4) ? Wn + (size_t)m * 16384 : Wsn + (size_t)(m - 4) * 16384;
    const float w = (n < 128) ? Wa[kg * 128 + n] : Wb[kg * 128 + (n - 128)];
    const unsigned short hi = f2bf(w);
    W3T[idx] = (bt < 4) ? hi : f2bf(w - bf2f(hi));
}

// finalize BN params from 64-replica stats; prm = [a1,c1,a2,c2]; re-zero reps
__global__ void bnfin_kernel(float* __restrict__ stats,
                             const float* __restrict__ bng, const float* __restrict__ bnb,
                             const float* __restrict__ bnsg, const float* __restrict__ bnsb,
                             float* __restrict__ prm)
{
    __shared__ float sN[256], sS[256];
    const int tid = threadIdx.x;
    float aN = 0.f, aS = 0.f;
    for (int r = 0; r < 64; ++r) {
        aN += stats[r * 256 + tid];
        aS += stats[16384 + r * 256 + tid];
    }
    sN[tid] = aN; sS[tid] = aS;
    __syncthreads();
    if (tid < 128) {
        const float mu = sN[tid] / (float)TN;
        const float var = sN[128 + tid] / (float)TN - mu * mu;
        const float a = bng[tid] / sqrtf(var + 1e-5f);
        prm[tid] = a;
        prm[128 + tid] = bnb[tid] - mu * a;
    } else {
        const int c = tid - 128;
        const float mu = sS[c] / (float)NSUB;
        const float var = sS[128 + c] / (float)NSUB - mu * mu;
        const float a = bnsg[c] / sqrtf(var + 1e-5f);
        prm[256 + c] = a;
        prm[384 + c] = bnsb[c] - mu * a;
    }
    for (int i = tid; i < 32768; i += 256) stats[i] = 0.f;
}

// graph pooling from XS (bf16): mean over n
__global__ void pool_kernel(const unsigned short* __restrict__ XS, float* __restrict__ hg)
{
    const int g = blockIdx.x, c = threadIdx.x;   // 128 threads
    float s = 0.f;
    for (int n = 0; n < 50; ++n)
        s += bf2f(XS[(size_t)(g * 50 + n) * 128 + c]);
    hg[g * 128 + c] = s * 0.02f;
}

__global__ void mlp_kernel(const float* __restrict__ hg,
                           const float* __restrict__ W1, const float* __restrict__ b1,
                           const float* __restrict__ W2, const float* __restrict__ b2,
                           float* __restrict__ out)
{
    __shared__ float xv[128];
    __shared__ float hid[256];
    const int g = blockIdx.x, tid = threadIdx.x;
    if (tid < 128) xv[tid] = hg[g * 128 + tid];
    __syncthreads();
    float a = b1[tid];
    for (int k = 0; k < 128; ++k) a += xv[k] * W1[k * 256 + tid];
    hid[tid] = fmaxf(a, 0.f);
    __syncthreads();
    if (tid < 10) {
        float o = b2[tid];
        for (int k = 0; k < 256; ++k) o += hid[k] * W2[k * 10 + tid];
        out[g * 10 + tid] = o;
    }
}

__global__ void zero_kernel(float* __restrict__ pz, int n)
{
    const int t = blockIdx.x * 256 + threadIdx.x;
    if (t < n) pz[t] = 0.f;
}

extern "C" void kernel_launch(void* const* d_in, const int* in_sizes, int n_in,
                              void* d_out, int out_size, void* d_ws, size_t ws_size,
                              hipStream_t stream)
{
    const float* x0   = (const float*)d_in[0];
    const float* Wr   = (const float*)d_in[1];
    const float* Wn   = (const float*)d_in[2];
    const float* bb   = (const float*)d_in[3];
    const float* bng  = (const float*)d_in[4];
    const float* bnb  = (const float*)d_in[5];
    const float* Wsr  = (const float*)d_in[6];
    const float* Wsn  = (const float*)d_in[7];
    const float* bs   = (const float*)d_in[8];
    const float* bnsg = (const float*)d_in[9];
    const float* bnsb = (const float*)d_in[10];
    const float* fW1  = (const float*)d_in[11];
    const float* fb1  = (const float*)d_in[12];
    const float* fW2  = (const float*)d_in[13];
    const float* fb2  = (const float*)d_in[14];
    const int* ei     = (const int*)d_in[15];
    const int* oei    = (const int*)d_in[16];
    float* out        = (float*)d_out;

    char* w = (char*)d_ws;
    unsigned short* A3  = (unsigned short*)w; w += (size_t)TN * 128 * 2;
    unsigned short* H1  = (unsigned short*)w; w += (size_t)TN * 128 * 2;
    unsigned short* W3T = (unsigned short*)w; w += (size_t)8 * 65536 * 2;
    unsigned short* XS  = (unsigned short*)w; w += (size_t)NSUB * 128 * 2;
    unsigned short* H2  = (unsigned short*)w; w += (size_t)NSUB * 128 * 2;
    unsigned short* AdjS = (unsigned short*)w; w += (size_t)NSUB * 3200 * 2;
    unsigned short* AdjO = (unsigned short*)w; w += (size_t)GG * 3200 * 2 + 4096;
    float* stats        = (float*)w;          w += (size_t)32768 * 4;  // [2][64][256]
    float* prm          = (float*)w;          w += 512 * 4;
    float* hg           = (float*)w;          w += (size_t)GG * 128 * 4;

    w3t_kernel<<<2048, 256, 0, stream>>>(Wr, Wn, Wsr, Wsn, W3T);
    adj_build<<<NSUB, 256, 0, stream>>>(ei, ei + 1280000, AdjS);
    adj_build<<<GG, 256, 0, stream>>>(oei, oei + 25600, AdjO);
    zero_kernel<<<128, 256, 0, stream>>>(stats, 32768);
    fusexsum_kernel<false><<<NSUB, 256, 0, stream>>>(x0, nullptr, nullptr, A3, XS);

    for (int i = 0; i < NL; ++i) {
        gconv_kernel<<<1632, 256, 0, stream>>>(A3, XS,
                                               W3T + (size_t)i * 65536,
                                               W3T + (size_t)(4 + i) * 65536,
                                               bb + i * 128, bs + i * 128,
                                               AdjS, AdjO, H1, H2, stats);
        bnfin_kernel<<<1, 256, 0, stream>>>(stats, bng + i * 128, bnb + i * 128,
                                            bnsg + i * 128, bnsb + i * 128, prm);
        fusexsum_kernel<true><<<NSUB, 256, 0, stream>>>(H1, H2, prm, A3, XS);
    }

    pool_kernel<<<GG, 128, 0, stream>>>(XS, hg);
    mlp_kernel<<<GG, 256, 0, stream>>>(hg, fW1, fb1, fW2, fb2, out);
}

// Round 13
// 371.899 us; speedup vs baseline: 1.5536x; 1.5536x over previous
//
#include <hip/hip_runtime.h>
#include <stdint.h>

#define D 128
#define TN 160000
#define NSUB 3200
#define GG 64
#define NL 4

typedef __bf16 bf16x8 __attribute__((ext_vector_type(8)));
typedef float f32x4 __attribute__((ext_vector_type(4)));
typedef unsigned int u32x4 __attribute__((ext_vector_type(4)));

__device__ __forceinline__ unsigned short f2bf(float v) {
    union { float f; uint32_t u; } c; c.f = v;
    uint32_t r = c.u + 0x7fffu + ((c.u >> 16) & 1u);
    return (unsigned short)(r >> 16);
}
__device__ __forceinline__ float bf2f(unsigned short h) {
    union { float f; uint32_t u; } c; c.u = ((uint32_t)h) << 16;
    return c.f;
}

__device__ __forceinline__ void gload16(const void* g, void* l) {
    __builtin_amdgcn_global_load_lds(
        (const __attribute__((address_space(1))) unsigned int*)g,
        (__attribute__((address_space(3))) unsigned int*)l, 16, 0, 0);
}

// ---------------------------------------------------------------------------
// Fused GraphConv, aggregation-as-MFMA (r11-proven config; 2 blocks/CU is the
// L2-capacity sweet spot — 3/CU thrashes the 4MB per-XCD L2, r12 evidence).
// Block = 2 units (100 rows) x 256 cols. Grid 1632: <1600 node-conv, rest
// subgraph-conv. Main GEMM: 2-term precision y = x_hi*(Whi+Wlo); A staged
// once (granule-XOR-swz); B wave-private ping-pong via global_load_lds (no
// block barriers in K-loop); m-frags per unit {0,16,32,34} (dups skipped).
// Aggregation: agg = Adj x Yn as MFMA; YnT bf16 [128][136]; Adj [2][50][64]
// bf16 (swz). H = Yr+agg+bias in regs -> bf16; BN stats -> 64-way replicas.
// ---------------------------------------------------------------------------
__global__ __launch_bounds__(256, 2)
void gconv_kernel(const unsigned short* __restrict__ A3,
                  const unsigned short* __restrict__ XS,
                  const unsigned short* __restrict__ Wt1,
                  const unsigned short* __restrict__ Wt2,
                  const float* __restrict__ bias1,
                  const float* __restrict__ bias2,
                  const unsigned short* __restrict__ AdjS,
                  const unsigned short* __restrict__ AdjO,
                  unsigned short* __restrict__ H1,
                  unsigned short* __restrict__ H2,
                  float* __restrict__ stats)
{
    __shared__ __align__(16) char lds[71680];
    // 0..25600        A [100][128] sh (swz)   -> later YnT [128][136] sh (0..34816)
    // 25600..58368    B: 4 waves x 2 x 4096B ping-pong
    // 58368..71168    Adj [2][50][64] sh (swz), +512B over-stage slack

    const int tid = threadIdx.x;
    const int blk = blockIdx.x;
    const bool big = blk < 1600;
    const int lb = big ? blk : blk - 1600;
    const unsigned short* Asrc = big ? A3 : XS;
    const unsigned short* Wt = big ? Wt1 : Wt2;
    const float* bias = big ? bias1 : bias2;
    const unsigned short* AdjG = (big ? AdjS : AdjO) + (size_t)lb * 6400;
    unsigned short* H = big ? H1 : H2;
    float* rep = stats + (big ? 0 : 16384) + (size_t)(lb & 63) * 256;
    const int rowbase = lb * 100;

    const int lane = tid & 63, wv = tid >> 6;
    const int p = lane & 15, q = lane >> 4;
    const int wn0 = wv * 64;

    // ---- phase 1: stage A (1600 granules, swz), Adj (800+slack), B0 ----
#pragma unroll
    for (int i = 0; i < 6; ++i) {
        const int c = i * 256 + tid;
        const int r = c >> 4, g = c & 15;
        gload16(Asrc + (size_t)(rowbase + r) * 128 + ((g ^ (r & 7)) << 3),
                lds + ((i * 256 + (wv << 6)) << 4));
    }
    if (wv == 0) {
        const int c = 1536 + lane;
        const int r = c >> 4, g = c & 15;
        gload16(Asrc + (size_t)(rowbase + r) * 128 + ((g ^ (r & 7)) << 3),
                lds + (1536 << 4));
    }
#pragma unroll
    for (int i = 0; i < 3; ++i) {
        const int c = i * 256 + tid;
        gload16(AdjG + (size_t)c * 8, lds + 58368 + ((i * 256 + (wv << 6)) << 4));
    }
    if (wv == 1) {   // granules 768..831 (last 32 are harmless over-stage)
        gload16(AdjG + (size_t)(768 + lane) * 8, lds + 58368 + (768 << 4));
    }
    {
        char* dst = lds + 25600 + ((wv * 2 + 0) << 12);
#pragma unroll
        for (int j = 0; j < 4; ++j)
            gload16(Wt + (size_t)wn0 * 32 + (size_t)(j * 64 + lane) * 8,
                    dst + (j << 10));
    }

    f32x4 acc[8][4];
#pragma unroll
    for (int i = 0; i < 8; ++i)
#pragma unroll
        for (int j = 0; j < 4; ++j) acc[i][j] = (f32x4){0.f, 0.f, 0.f, 0.f};

    __syncthreads();   // barrier 1

    // ---- phase 2: K-loop, 8 tiles, wave-private B ping-pong ----
    static const int FR[8] = {0, 16, 32, 34, 50, 66, 82, 84};
    const unsigned short* Ash = (const unsigned short*)lds;
#pragma unroll
    for (int t = 0; t < 8; ++t) {
        if (t > 0) asm volatile("s_waitcnt vmcnt(0)" ::: "memory");
        const unsigned short* Bw =
            (const unsigned short*)(lds + 25600 + ((wv * 2 + (t & 1)) << 12));
        bf16x8 bfr[4];
#pragma unroll
        for (int ni = 0; ni < 4; ++ni) {
            u32x4 raw = *(const u32x4*)&Bw[(ni * 16 + p) * 32 + q * 8];
            bfr[ni] = __builtin_bit_cast(bf16x8, raw);
        }
        if (t < 7) {
            char* dst = lds + 25600 + ((wv * 2 + ((t + 1) & 1)) << 12);
#pragma unroll
            for (int j = 0; j < 4; ++j)
                gload16(Wt + ((size_t)(t + 1) << 13) + (size_t)wn0 * 32 +
                            (size_t)(j * 64 + lane) * 8,
                        dst + (j << 10));
        }
        const int gb = (t & 3) * 4 + q;
        __builtin_amdgcn_s_setprio(1);
#pragma unroll
        for (int mi = 0; mi < 8; ++mi) {
            const int rr = FR[mi] + p;
            u32x4 raw = *(const u32x4*)&Ash[rr * 128 + ((gb ^ (rr & 7)) << 3)];
            bf16x8 afr = __builtin_bit_cast(bf16x8, raw);
#pragma unroll
            for (int ni = 0; ni < 4; ++ni)
                acc[mi][ni] = __builtin_amdgcn_mfma_f32_16x16x32_bf16(afr, bfr[ni], acc[mi][ni], 0, 0, 0);
        }
        __builtin_amdgcn_s_setprio(0);
    }

    __syncthreads();   // barrier 2: all A/B reads done; A+B region reusable

    // ---- phase 3: waves 2,3 dump YnT (bf16, transposed); waves 0,1 zero pad
    static const int F4[4] = {0, 16, 32, 34};
    unsigned short* YnT = (unsigned short*)lds;
    if (wv >= 2) {
        const int cb = (wv - 2) * 64;
#pragma unroll
        for (int u = 0; u < 2; ++u)
#pragma unroll
            for (int fi = 0; fi < 4; ++fi) {
#pragma unroll
                for (int rp = 0; rp < 4; rp += 2) {
                    if (fi == 3 && (q * 4 + rp) < 14) continue;
                    const int jl = F4[fi] + q * 4 + rp;
#pragma unroll
                    for (int ni = 0; ni < 4; ++ni) {
                        const int c = cb + ni * 16 + p;
                        const uint32_t v =
                            (uint32_t)f2bf(acc[u * 4 + fi][ni][rp]) |
                            ((uint32_t)f2bf(acc[u * 4 + fi][ni][rp + 1]) << 16);
                        *(uint32_t*)&YnT[c * 136 + u * 64 + jl] = v;
                    }
                }
            }
    } else {
        const int c = wv * 64 + lane;   // 128 threads cover all cols
#pragma unroll
        for (int u = 0; u < 2; ++u)
#pragma unroll
            for (int k = 0; k < 7; ++k)
                *(uint32_t*)&YnT[c * 136 + u * 64 + 50 + k * 2] = 0;
    }
    __syncthreads();   // barrier 3

    // ---- phase 4: waves 0,1: agg = Adj x YnT (MFMA), H = Yr+agg+bias ----
    if (wv < 2) {
        const int cb = wv * 64;
        const unsigned short* AdjL = (const unsigned short*)(lds + 58368);
        float sm[4] = {0.f, 0.f, 0.f, 0.f}, sq[4] = {0.f, 0.f, 0.f, 0.f};
        float bv[4];
#pragma unroll
        for (int ni = 0; ni < 4; ++ni) bv[ni] = bias[cb + ni * 16 + p];
#pragma unroll
        for (int u = 0; u < 2; ++u) {
            f32x4 aacc[4][4];
#pragma unroll
            for (int i = 0; i < 4; ++i)
#pragma unroll
                for (int j = 0; j < 4; ++j) aacc[i][j] = (f32x4){0.f, 0.f, 0.f, 0.f};
#pragma unroll
            for (int ks = 0; ks < 2; ++ks) {
                bf16x8 afr[4], bfr2[4];
#pragma unroll
                for (int fi = 0; fi < 4; ++fi) {
                    const int m = F4[fi] + p;
                    const int gi = ks * 4 + q;
                    u32x4 raw = *(const u32x4*)&AdjL[(u * 50 + m) * 64 + ((gi ^ (m & 7)) << 3)];
                    afr[fi] = __builtin_bit_cast(bf16x8, raw);
                }
#pragma unroll
                for (int ni = 0; ni < 4; ++ni) {
                    u32x4 raw = *(const u32x4*)&YnT[(cb + ni * 16 + p) * 136 + u * 64 + ks * 32 + q * 8];
                    bfr2[ni] = __builtin_bit_cast(bf16x8, raw);
                }
#pragma unroll
                for (int fi = 0; fi < 4; ++fi)
#pragma unroll
                    for (int ni = 0; ni < 4; ++ni)
                        aacc[fi][ni] = __builtin_amdgcn_mfma_f32_16x16x32_bf16(afr[fi], bfr2[ni], aacc[fi][ni], 0, 0, 0);
            }
#pragma unroll
            for (int fi = 0; fi < 4; ++fi)
#pragma unroll
                for (int r = 0; r < 4; ++r) {
                    if (fi == 3 && (q * 4 + r) < 14) continue;
                    const int row = u * 50 + F4[fi] + q * 4 + r;
#pragma unroll
                    for (int ni = 0; ni < 4; ++ni) {
                        const int cc = cb + ni * 16 + p;
                        const float h = acc[u * 4 + fi][ni][r] + aacc[fi][ni][r] + bv[ni];
                        H[(size_t)(rowbase + row) * 128 + cc] = f2bf(h);
                        sm[ni] += h; sq[ni] += h * h;
                    }
                }
        }
#pragma unroll
        for (int ni = 0; ni < 4; ++ni) {
            atomicAdd(&rep[cb + ni * 16 + p], sm[ni]);
            atomicAdd(&rep[128 + cb + ni * 16 + p], sq[ni]);
        }
    }
}

// ---------------------------------------------------------------------------
// adj_build: one block per unit. Dense [50][64] multiplicity matrix in LDS,
// written out bf16 ([50][64] = 3200 shorts per unit, contiguous across units)
// with the gconv granule swizzle pre-applied.
// ---------------------------------------------------------------------------
__global__ void adj_build(const int* __restrict__ src, const int* __restrict__ dst,
                          unsigned short* __restrict__ AdjG)
{
    __shared__ int cnt[3200];
    const int u = blockIdx.x, t = threadIdx.x;
    for (int i = t; i < 3200; i += 256) cnt[i] = 0;
    __syncthreads();
    for (int e = t; e < 400; e += 256) {
        const int d = dst[u * 400 + e] - u * 50;
        const int s = src[u * 400 + e] - u * 50;
        atomicAdd(&cnt[d * 64 + s], 1);
    }
    __syncthreads();
    for (int i = t; i < 3200; i += 256) {
        const int m = i >> 6, j = i & 63;
        const float v = (float)cnt[i];
        const int pos = m * 64 + ((((j >> 3) ^ (m & 7)) << 3) | (j & 7));
        AdjG[(size_t)u * 3200 + pos] = f2bf(v);
    }
}

// ---------------------------------------------------------------------------
// fuse (BN1+BN2[node_idx]+relu) + bf16 -> A3 (hi only), subgraph-mean -> XS.
// Vectorized: each thread owns a channel PAIR (uint = 2 bf16, 4B/lane).
// 4 row-groups of 13/13/12/12 s-values. WRA3=false on the last layer.
// ---------------------------------------------------------------------------
template <bool FUSE, bool WRA3>
__global__ __launch_bounds__(256)
void fusexsum_kernel(const void* __restrict__ HPv,
                     const unsigned short* __restrict__ H2,
                     const float* __restrict__ prm,
                     unsigned short* __restrict__ A3,
                     unsigned short* __restrict__ XS)
{
    __shared__ float red[512];
    const unsigned short* HPb = (const unsigned short*)HPv;
    const float* HPf = (const float*)HPv;
    const int blk = blockIdx.x;          // g*50 + n
    const int g = blk / 50, n = blk - g * 50;
    const int tid = threadIdx.x;
    const int cp = tid & 63;             // channel pair -> channels 2cp, 2cp+1
    const int grp = tid >> 6;            // 0..3
    const int c0 = cp * 2, c1 = c0 + 1;
    float a1x = 0.f, b1x = 0.f, hh0 = 0.f, a1y = 0.f, b1y = 0.f, hh1 = 0.f;
    if (FUSE) {
        a1x = prm[c0]; b1x = prm[128 + c0];
        a1y = prm[c1]; b1y = prm[128 + c1];
        const uint32_t h2v = *(const uint32_t*)&H2[(size_t)blk * 128 + c0];
        hh0 = prm[256 + c0] * bf2f((unsigned short)(h2v & 0xffff)) + prm[384 + c0];
        hh1 = prm[256 + c1] * bf2f((unsigned short)(h2v >> 16)) + prm[384 + c1];
    }
    float acc0 = 0.f, acc1 = 0.f;
    const int sBeg = (grp < 2) ? grp * 13 : 26 + (grp - 2) * 12;
    const int sEnd = sBeg + ((grp < 2) ? 13 : 12);
    for (int s = sBeg; s < sEnd; ++s) {
        const size_t row = (size_t)g * 2500 + s * 50 + n;
        float v0, v1;
        if (FUSE) {
            const uint32_t hv = *(const uint32_t*)&HPb[row * 128 + c0];
            v0 = fmaxf(0.f, a1x * bf2f((unsigned short)(hv & 0xffff)) + b1x + hh0);
            v1 = fmaxf(0.f, a1y * bf2f((unsigned short)(hv >> 16)) + b1y + hh1);
        } else {
            v0 = HPf[row * 128 + c0];
            v1 = HPf[row * 128 + c1];
        }
        if (WRA3) {
            const uint32_t o = (uint32_t)f2bf(v0) | ((uint32_t)f2bf(v1) << 16);
            *(uint32_t*)&A3[row * 128 + c0] = o;
        }
        acc0 += v0; acc1 += v1;
    }
    red[tid * 2] = acc0; red[tid * 2 + 1] = acc1;
    __syncthreads();
    if (tid < 64) {
        float s0 = 0.f, s1 = 0.f;
        for (int gp = 0; gp < 4; ++gp) {
            s0 += red[(gp * 64 + tid) * 2];
            s1 += red[(gp * 64 + tid) * 2 + 1];
        }
        const uint32_t o = (uint32_t)f2bf(s0 * 0.02f) | ((uint32_t)f2bf(s1 * 0.02f) << 16);
        *(uint32_t*)&XS[(size_t)blk * 128 + tid * 2] = o;
    }
}

// build W3T: 8 matrices x 8 tiles x [256 n][32 k] bf16; tiles 0-3 = hi(W),
// tiles 4-7 = lo(W) k-slices.
__global__ void w3t_kernel(const float* __restrict__ Wr, const float* __restrict__ Wn,
                           const float* __restrict__ Wsr, const float* __restrict__ Wsn,
                           unsigned short* __restrict__ W3T)
{
    const int idx = blockIdx.x * 256 + threadIdx.x;  // 8*65536
    const int m = idx >> 16;
    const int r = idx & 65535;
    const int bt = r >> 13;
    const int rr = r & 8191;
    const int n = rr >> 5, kloc = rr & 31;
    const int kg = (bt & 3) * 32 + kloc;
    const float* Wa = (m < 4) ? Wr + (size_t)m * 16384 : Wsr + (size_t)(m - 4) * 16384;
    const float* Wb = (m < 4) ? Wn + (size_t)m * 16384 : Wsn + (size_t)(m - 4) * 16384;
    const float w = (n < 128) ? Wa[kg * 128 + n] : Wb[kg * 128 + (n - 128)];
    const unsigned short hi = f2bf(w);
    W3T[idx] = (bt < 4) ? hi : f2bf(w - bf2f(hi));
}

// finalize BN params from 64-replica stats; prm = [a1,c1,a2,c2]; re-zero reps
__global__ void bnfin_kernel(float* __restrict__ stats,
                             const float* __restrict__ bng, const float* __restrict__ bnb,
                             const float* __restrict__ bnsg, const float* __restrict__ bnsb,
                             float* __restrict__ prm)
{
    __shared__ float sN[256], sS[256];
    const int tid = threadIdx.x;
    float aN = 0.f, aS = 0.f;
    for (int r = 0; r < 64; ++r) {
        aN += stats[r * 256 + tid];
        aS += stats[16384 + r * 256 + tid];
    }
    sN[tid] = aN; sS[tid] = aS;
    __syncthreads();
    if (tid < 128) {
        const float mu = sN[tid] / (float)TN;
        const float var = sN[128 + tid] / (float)TN - mu * mu;
        const float a = bng[tid] / sqrtf(var + 1e-5f);
        prm[tid] = a;
        prm[128 + tid] = bnb[tid] - mu * a;
    } else {
        const int c = tid - 128;
        const float mu = sS[c] / (float)NSUB;
        const float var = sS[128 + c] / (float)NSUB - mu * mu;
        const float a = bnsg[c] / sqrtf(var + 1e-5f);
        prm[256 + c] = a;
        prm[384 + c] = bnsb[c] - mu * a;
    }
    for (int i = tid; i < 32768; i += 256) stats[i] = 0.f;
}

// graph pooling from XS (bf16): mean over n
__global__ void pool_kernel(const unsigned short* __restrict__ XS, float* __restrict__ hg)
{
    const int g = blockIdx.x, c = threadIdx.x;   // 128 threads
    float s = 0.f;
    for (int n = 0; n < 50; ++n)
        s += bf2f(XS[(size_t)(g * 50 + n) * 128 + c]);
    hg[g * 128 + c] = s * 0.02f;
}

__global__ void mlp_kernel(const float* __restrict__ hg,
                           const float* __restrict__ W1, const float* __restrict__ b1,
                           const float* __restrict__ W2, const float* __restrict__ b2,
                           float* __restrict__ out)
{
    __shared__ float xv[128];
    __shared__ float hid[256];
    const int g = blockIdx.x, tid = threadIdx.x;
    if (tid < 128) xv[tid] = hg[g * 128 + tid];
    __syncthreads();
    float a = b1[tid];
    for (int k = 0; k < 128; ++k) a += xv[k] * W1[k * 256 + tid];
    hid[tid] = fmaxf(a, 0.f);
    __syncthreads();
    if (tid < 10) {
        float o = b2[tid];
        for (int k = 0; k < 256; ++k) o += hid[k] * W2[k * 10 + tid];
        out[g * 10 + tid] = o;
    }
}

__global__ void zero_kernel(float* __restrict__ pz, int n)
{
    const int t = blockIdx.x * 256 + threadIdx.x;
    if (t < n) pz[t] = 0.f;
}

extern "C" void kernel_launch(void* const* d_in, const int* in_sizes, int n_in,
                              void* d_out, int out_size, void* d_ws, size_t ws_size,
                              hipStream_t stream)
{
    const float* x0   = (const float*)d_in[0];
    const float* Wr   = (const float*)d_in[1];
    const float* Wn   = (const float*)d_in[2];
    const float* bb   = (const float*)d_in[3];
    const float* bng  = (const float*)d_in[4];
    const float* bnb  = (const float*)d_in[5];
    const float* Wsr  = (const float*)d_in[6];
    const float* Wsn  = (const float*)d_in[7];
    const float* bs   = (const float*)d_in[8];
    const float* bnsg = (const float*)d_in[9];
    const float* bnsb = (const float*)d_in[10];
    const float* fW1  = (const float*)d_in[11];
    const float* fb1  = (const float*)d_in[12];
    const float* fW2  = (const float*)d_in[13];
    const float* fb2  = (const float*)d_in[14];
    const int* ei     = (const int*)d_in[15];
    const int* oei    = (const int*)d_in[16];
    float* out        = (float*)d_out;

    char* w = (char*)d_ws;
    unsigned short* A3  = (unsigned short*)w; w += (size_t)TN * 128 * 2;
    unsigned short* H1  = (unsigned short*)w; w += (size_t)TN * 128 * 2;
    unsigned short* W3T = (unsigned short*)w; w += (size_t)8 * 65536 * 2;
    unsigned short* XS  = (unsigned short*)w; w += (size_t)NSUB * 128 * 2;
    unsigned short* H2  = (unsigned short*)w; w += (size_t)NSUB * 128 * 2;
    unsigned short* AdjS = (unsigned short*)w; w += (size_t)NSUB * 3200 * 2;
    unsigned short* AdjO = (unsigned short*)w; w += (size_t)GG * 3200 * 2 + 4096;
    float* stats        = (float*)w;          w += (size_t)32768 * 4;  // [2][64][256]
    float* prm          = (float*)w;          w += 512 * 4;
    float* hg           = (float*)w;          w += (size_t)GG * 128 * 4;

    w3t_kernel<<<2048, 256, 0, stream>>>(Wr, Wn, Wsr, Wsn, W3T);
    adj_build<<<NSUB, 256, 0, stream>>>(ei, ei + 1280000, AdjS);
    adj_build<<<GG, 256, 0, stream>>>(oei, oei + 25600, AdjO);
    zero_kernel<<<128, 256, 0, stream>>>(stats, 32768);
    fusexsum_kernel<false, true><<<NSUB, 256, 0, stream>>>(x0, nullptr, nullptr, A3, XS);

    for (int i = 0; i < NL; ++i) {
        gconv_kernel<<<1632, 256, 0, stream>>>(A3, XS,
                                               W3T + (size_t)i * 65536,
                                               W3T + (size_t)(4 + i) * 65536,
                                               bb + i * 128, bs + i * 128,
                                               AdjS, AdjO, H1, H2, stats);
        bnfin_kernel<<<1, 256, 0, stream>>>(stats, bng + i * 128, bnb + i * 128,
                                            bnsg + i * 128, bnsb + i * 128, prm);
        if (i < NL - 1)
            fusexsum_kernel<true, true><<<NSUB, 256, 0, stream>>>(H1, H2, prm, A3, XS);
        else
            fusexsum_kernel<true, false><<<NSUB, 256, 0, stream>>>(H1, H2, prm, A3, XS);
    }

    pool_kernel<<<GG, 128, 0, stream>>>(XS, hg);
    mlp_kernel<<<GG, 256, 0, stream>>>(hg, fW1, fb1, fW2, fb2, out);
}

// Round 14
// 364.539 us; speedup vs baseline: 1.5850x; 1.0202x over previous
//
#include <hip/hip_runtime.h>
#include <stdint.h>

#define D 128
#define TN 160000
#define NSUB 3200
#define GG 64
#define NL 4

typedef __bf16 bf16x8 __attribute__((ext_vector_type(8)));
typedef float f32x4 __attribute__((ext_vector_type(4)));
typedef unsigned int u32x4 __attribute__((ext_vector_type(4)));

__device__ __forceinline__ unsigned short f2bf(float v) {
    union { float f; uint32_t u; } c; c.f = v;
    uint32_t r = c.u + 0x7fffu + ((c.u >> 16) & 1u);
    return (unsigned short)(r >> 16);
}
__device__ __forceinline__ float bf2f(unsigned short h) {
    union { float f; uint32_t u; } c; c.u = ((uint32_t)h) << 16;
    return c.f;
}

__device__ __forceinline__ void gload16(const void* g, void* l) {
    __builtin_amdgcn_global_load_lds(
        (const __attribute__((address_space(1))) unsigned int*)g,
        (__attribute__((address_space(3))) unsigned int*)l, 16, 0, 0);
}

// ---------------------------------------------------------------------------
// Fused GraphConv, aggregation-as-MFMA (r11/r13-proven config; 2 blocks/CU is
// the L2-capacity sweet spot — 3/CU thrashes the 4MB per-XCD L2, r12).
// Block = 2 units (100 rows) x 256 cols. Grid 1632: <1600 node-conv, rest
// subgraph-conv. Main GEMM: 2-term precision y = x_hi*(Whi+Wlo); A staged
// once (granule-XOR-swz); B wave-private ping-pong via global_load_lds (no
// block barriers in K-loop); m-frags per unit {0,16,32,34} (dups skipped).
// Aggregation: agg = Adj x Yn as MFMA; YnT bf16 [128][136]; Adj [2][50][64]
// bf16 (swz). H = Yr+agg+bias in regs -> bf16; BN stats -> 32-way replicas
// in this layer's slice statsL[2][32][256].
// ---------------------------------------------------------------------------
__global__ __launch_bounds__(256, 2)
void gconv_kernel(const unsigned short* __restrict__ A3,
                  const unsigned short* __restrict__ XS,
                  const unsigned short* __restrict__ Wt1,
                  const unsigned short* __restrict__ Wt2,
                  const float* __restrict__ bias1,
                  const float* __restrict__ bias2,
                  const unsigned short* __restrict__ AdjS,
                  const unsigned short* __restrict__ AdjO,
                  unsigned short* __restrict__ H1,
                  unsigned short* __restrict__ H2,
                  float* __restrict__ statsL)
{
    __shared__ __align__(16) char lds[71680];
    // 0..25600        A [100][128] sh (swz)   -> later YnT [128][136] sh (0..34816)
    // 25600..58368    B: 4 waves x 2 x 4096B ping-pong
    // 58368..71168    Adj [2][50][64] sh (swz), +512B over-stage slack

    const int tid = threadIdx.x;
    const int blk = blockIdx.x;
    const bool big = blk < 1600;
    const int lb = big ? blk : blk - 1600;
    const unsigned short* Asrc = big ? A3 : XS;
    const unsigned short* Wt = big ? Wt1 : Wt2;
    const float* bias = big ? bias1 : bias2;
    const unsigned short* AdjG = (big ? AdjS : AdjO) + (size_t)lb * 6400;
    unsigned short* H = big ? H1 : H2;
    float* rep = statsL + (big ? 0 : 8192) + (size_t)(lb & 31) * 256;
    const int rowbase = lb * 100;

    const int lane = tid & 63, wv = tid >> 6;
    const int p = lane & 15, q = lane >> 4;
    const int wn0 = wv * 64;

    // ---- phase 1: stage A (1600 granules, swz), Adj (800+slack), B0 ----
#pragma unroll
    for (int i = 0; i < 6; ++i) {
        const int c = i * 256 + tid;
        const int r = c >> 4, g = c & 15;
        gload16(Asrc + (size_t)(rowbase + r) * 128 + ((g ^ (r & 7)) << 3),
                lds + ((i * 256 + (wv << 6)) << 4));
    }
    if (wv == 0) {
        const int c = 1536 + lane;
        const int r = c >> 4, g = c & 15;
        gload16(Asrc + (size_t)(rowbase + r) * 128 + ((g ^ (r & 7)) << 3),
                lds + (1536 << 4));
    }
#pragma unroll
    for (int i = 0; i < 3; ++i) {
        const int c = i * 256 + tid;
        gload16(AdjG + (size_t)c * 8, lds + 58368 + ((i * 256 + (wv << 6)) << 4));
    }
    if (wv == 1) {   // granules 768..831 (last 32 are harmless over-stage)
        gload16(AdjG + (size_t)(768 + lane) * 8, lds + 58368 + (768 << 4));
    }
    {
        char* dst = lds + 25600 + ((wv * 2 + 0) << 12);
#pragma unroll
        for (int j = 0; j < 4; ++j)
            gload16(Wt + (size_t)wn0 * 32 + (size_t)(j * 64 + lane) * 8,
                    dst + (j << 10));
    }

    f32x4 acc[8][4];
#pragma unroll
    for (int i = 0; i < 8; ++i)
#pragma unroll
        for (int j = 0; j < 4; ++j) acc[i][j] = (f32x4){0.f, 0.f, 0.f, 0.f};

    __syncthreads();   // barrier 1

    // ---- phase 2: K-loop, 8 tiles, wave-private B ping-pong ----
    static const int FR[8] = {0, 16, 32, 34, 50, 66, 82, 84};
    const unsigned short* Ash = (const unsigned short*)lds;
#pragma unroll
    for (int t = 0; t < 8; ++t) {
        if (t > 0) asm volatile("s_waitcnt vmcnt(0)" ::: "memory");
        const unsigned short* Bw =
            (const unsigned short*)(lds + 25600 + ((wv * 2 + (t & 1)) << 12));
        bf16x8 bfr[4];
#pragma unroll
        for (int ni = 0; ni < 4; ++ni) {
            u32x4 raw = *(const u32x4*)&Bw[(ni * 16 + p) * 32 + q * 8];
            bfr[ni] = __builtin_bit_cast(bf16x8, raw);
        }
        if (t < 7) {
            char* dst = lds + 25600 + ((wv * 2 + ((t + 1) & 1)) << 12);
#pragma unroll
            for (int j = 0; j < 4; ++j)
                gload16(Wt + ((size_t)(t + 1) << 13) + (size_t)wn0 * 32 +
                            (size_t)(j * 64 + lane) * 8,
                        dst + (j << 10));
        }
        const int gb = (t & 3) * 4 + q;
        __builtin_amdgcn_s_setprio(1);
#pragma unroll
        for (int mi = 0; mi < 8; ++mi) {
            const int rr = FR[mi] + p;
            u32x4 raw = *(const u32x4*)&Ash[rr * 128 + ((gb ^ (rr & 7)) << 3)];
            bf16x8 afr = __builtin_bit_cast(bf16x8, raw);
#pragma unroll
            for (int ni = 0; ni < 4; ++ni)
                acc[mi][ni] = __builtin_amdgcn_mfma_f32_16x16x32_bf16(afr, bfr[ni], acc[mi][ni], 0, 0, 0);
        }
        __builtin_amdgcn_s_setprio(0);
    }

    __syncthreads();   // barrier 2: all A/B reads done; A+B region reusable

    // ---- phase 3: waves 2,3 dump YnT (bf16, transposed); waves 0,1 zero pad
    static const int F4[4] = {0, 16, 32, 34};
    unsigned short* YnT = (unsigned short*)lds;
    if (wv >= 2) {
        const int cb = (wv - 2) * 64;
#pragma unroll
        for (int u = 0; u < 2; ++u)
#pragma unroll
            for (int fi = 0; fi < 4; ++fi) {
#pragma unroll
                for (int rp = 0; rp < 4; rp += 2) {
                    if (fi == 3 && (q * 4 + rp) < 14) continue;
                    const int jl = F4[fi] + q * 4 + rp;
#pragma unroll
                    for (int ni = 0; ni < 4; ++ni) {
                        const int c = cb + ni * 16 + p;
                        const uint32_t v =
                            (uint32_t)f2bf(acc[u * 4 + fi][ni][rp]) |
                            ((uint32_t)f2bf(acc[u * 4 + fi][ni][rp + 1]) << 16);
                        *(uint32_t*)&YnT[c * 136 + u * 64 + jl] = v;
                    }
                }
            }
    } else {
        const int c = wv * 64 + lane;   // 128 threads cover all cols
#pragma unroll
        for (int u = 0; u < 2; ++u)
#pragma unroll
            for (int k = 0; k < 7; ++k)
                *(uint32_t*)&YnT[c * 136 + u * 64 + 50 + k * 2] = 0;
    }
    __syncthreads();   // barrier 3

    // ---- phase 4: waves 0,1: agg = Adj x YnT (MFMA), H = Yr+agg+bias ----
    if (wv < 2) {
        const int cb = wv * 64;
        const unsigned short* AdjL = (const unsigned short*)(lds + 58368);
        float sm[4] = {0.f, 0.f, 0.f, 0.f}, sq[4] = {0.f, 0.f, 0.f, 0.f};
        float bv[4];
#pragma unroll
        for (int ni = 0; ni < 4; ++ni) bv[ni] = bias[cb + ni * 16 + p];
#pragma unroll
        for (int u = 0; u < 2; ++u) {
            f32x4 aacc[4][4];
#pragma unroll
            for (int i = 0; i < 4; ++i)
#pragma unroll
                for (int j = 0; j < 4; ++j) aacc[i][j] = (f32x4){0.f, 0.f, 0.f, 0.f};
#pragma unroll
            for (int ks = 0; ks < 2; ++ks) {
                bf16x8 afr[4], bfr2[4];
#pragma unroll
                for (int fi = 0; fi < 4; ++fi) {
                    const int m = F4[fi] + p;
                    const int gi = ks * 4 + q;
                    u32x4 raw = *(const u32x4*)&AdjL[(u * 50 + m) * 64 + ((gi ^ (m & 7)) << 3)];
                    afr[fi] = __builtin_bit_cast(bf16x8, raw);
                }
#pragma unroll
                for (int ni = 0; ni < 4; ++ni) {
                    u32x4 raw = *(const u32x4*)&YnT[(cb + ni * 16 + p) * 136 + u * 64 + ks * 32 + q * 8];
                    bfr2[ni] = __builtin_bit_cast(bf16x8, raw);
                }
#pragma unroll
                for (int fi = 0; fi < 4; ++fi)
#pragma unroll
                    for (int ni = 0; ni < 4; ++ni)
                        aacc[fi][ni] = __builtin_amdgcn_mfma_f32_16x16x32_bf16(afr[fi], bfr2[ni], aacc[fi][ni], 0, 0, 0);
            }
#pragma unroll
            for (int fi = 0; fi < 4; ++fi)
#pragma unroll
                for (int r = 0; r < 4; ++r) {
                    if (fi == 3 && (q * 4 + r) < 14) continue;
                    const int row = u * 50 + F4[fi] + q * 4 + r;
#pragma unroll
                    for (int ni = 0; ni < 4; ++ni) {
                        const int cc = cb + ni * 16 + p;
                        const float h = acc[u * 4 + fi][ni][r] + aacc[fi][ni][r] + bv[ni];
                        H[(size_t)(rowbase + row) * 128 + cc] = f2bf(h);
                        sm[ni] += h; sq[ni] += h * h;
                    }
                }
        }
#pragma unroll
        for (int ni = 0; ni < 4; ++ni) {
            atomicAdd(&rep[cb + ni * 16 + p], sm[ni]);
            atomicAdd(&rep[128 + cb + ni * 16 + p], sq[ni]);
        }
    }
}

// ---------------------------------------------------------------------------
// adj body (device): dense [50][64] multiplicity matrix in LDS, written bf16
// ([50][64] = 3200 shorts/unit, contiguous) with gconv granule swizzle.
// ---------------------------------------------------------------------------
__device__ __forceinline__ void adj_body(int u, const int* __restrict__ src,
                                         const int* __restrict__ dst,
                                         unsigned short* __restrict__ AdjG,
                                         int* cnt)
{
    const int t = threadIdx.x;
    for (int i = t; i < 3200; i += 256) cnt[i] = 0;
    __syncthreads();
    for (int e = t; e < 400; e += 256) {
        const int d = dst[u * 400 + e] - u * 50;
        const int s = src[u * 400 + e] - u * 50;
        atomicAdd(&cnt[d * 64 + s], 1);
    }
    __syncthreads();
    for (int i = t; i < 3200; i += 256) {
        const int m = i >> 6, j = i & 63;
        const float v = (float)cnt[i];
        const int pos = m * 64 + ((((j >> 3) ^ (m & 7)) << 3) | (j & 7));
        AdjG[(size_t)u * 3200 + pos] = f2bf(v);
    }
}

// ---------------------------------------------------------------------------
// setup: blocks [0,2048) build W3T; [2048,5248) AdjS; [5248,5312) AdjO;
// [5312,5568) zero the 4-layer stats (65536 floats).
// W3T: 8 matrices x 8 tiles x [256 n][32 k] bf16; tiles 0-3 hi(W), 4-7 lo(W).
// ---------------------------------------------------------------------------
__global__ __launch_bounds__(256)
void setup_kernel(const float* __restrict__ Wr, const float* __restrict__ Wn,
                  const float* __restrict__ Wsr, const float* __restrict__ Wsn,
                  unsigned short* __restrict__ W3T,
                  const int* __restrict__ ei, const int* __restrict__ oei,
                  unsigned short* __restrict__ AdjS,
                  unsigned short* __restrict__ AdjO,
                  float* __restrict__ stats)
{
    __shared__ int cnt[3200];
    const int b = blockIdx.x, t = threadIdx.x;
    if (b < 2048) {
        const int idx = b * 256 + t;
        const int m = idx >> 16;
        const int r = idx & 65535;
        const int bt = r >> 13;
        const int rr = r & 8191;
        const int n = rr >> 5, kloc = rr & 31;
        const int kg = (bt & 3) * 32 + kloc;
        const float* Wa = (m < 4) ? Wr + (size_t)m * 16384 : Wsr + (size_t)(m - 4) * 16384;
        const float* Wb = (m < 4) ? Wn + (size_t)m * 16384 : Wsn + (size_t)(m - 4) * 16384;
        const float w = (n < 128) ? Wa[kg * 128 + n] : Wb[kg * 128 + (n - 128)];
        const unsigned short hi = f2bf(w);
        W3T[idx] = (bt < 4) ? hi : f2bf(w - bf2f(hi));
    } else if (b < 5248) {
        adj_body(b - 2048, ei, ei + 1280000, AdjS, cnt);
    } else if (b < 5312) {
        adj_body(b - 5248, oei, oei + 25600, AdjO, cnt);
    } else {
        stats[(b - 5312) * 256 + t] = 0.f;
    }
}

// ---------------------------------------------------------------------------
// fusexsum: inline BN-param computation from this layer's stats slice
// (statsL[2][32][256], exact bnfin math), then
// x = relu(a1*h1 + c1 + a2*h2[node_idx] + c2) -> A3 bf16 (if WRA3), and
// subgraph-mean -> XS. Thread owns a channel pair (4B/lane); 4 row-groups.
// ---------------------------------------------------------------------------
template <bool FUSE, bool WRA3>
__global__ __launch_bounds__(256)
void fusexsum_kernel(const void* __restrict__ HPv,
                     const unsigned short* __restrict__ H2,
                     const float* __restrict__ statsL,
                     const float* __restrict__ bng, const float* __restrict__ bnb,
                     const float* __restrict__ bnsg, const float* __restrict__ bnsb,
                     unsigned short* __restrict__ A3,
                     unsigned short* __restrict__ XS)
{
    __shared__ float red[512];
    __shared__ float prmL[512];
    __shared__ float sN[256], sS[256];
    const unsigned short* HPb = (const unsigned short*)HPv;
    const float* HPf = (const float*)HPv;
    const int blk = blockIdx.x;          // g*50 + n
    const int g = blk / 50, n = blk - g * 50;
    const int tid = threadIdx.x;
    const int cp = tid & 63;             // channel pair -> channels 2cp, 2cp+1
    const int grp = tid >> 6;            // 0..3
    const int c0 = cp * 2, c1 = c0 + 1;

    if (FUSE) {
        float aN = 0.f, aS = 0.f;
#pragma unroll
        for (int r = 0; r < 32; ++r) {
            aN += statsL[r * 256 + tid];
            aS += statsL[8192 + r * 256 + tid];
        }
        sN[tid] = aN; sS[tid] = aS;
        __syncthreads();
        if (tid < 128) {
            const float mu = sN[tid] / (float)TN;
            const float var = sN[128 + tid] / (float)TN - mu * mu;
            const float a = bng[tid] / sqrtf(var + 1e-5f);
            prmL[tid] = a;
            prmL[128 + tid] = bnb[tid] - mu * a;
        } else {
            const int c = tid - 128;
            const float mu = sS[c] / (float)NSUB;
            const float var = sS[128 + c] / (float)NSUB - mu * mu;
            const float a = bnsg[c] / sqrtf(var + 1e-5f);
            prmL[256 + c] = a;
            prmL[384 + c] = bnsb[c] - mu * a;
        }
        __syncthreads();
    }

    float a1x = 0.f, b1x = 0.f, hh0 = 0.f, a1y = 0.f, b1y = 0.f, hh1 = 0.f;
    if (FUSE) {
        a1x = prmL[c0]; b1x = prmL[128 + c0];
        a1y = prmL[c1]; b1y = prmL[128 + c1];
        const uint32_t h2v = *(const uint32_t*)&H2[(size_t)blk * 128 + c0];
        hh0 = prmL[256 + c0] * bf2f((unsigned short)(h2v & 0xffff)) + prmL[384 + c0];
        hh1 = prmL[256 + c1] * bf2f((unsigned short)(h2v >> 16)) + prmL[384 + c1];
    }
    float acc0 = 0.f, acc1 = 0.f;
    const int sBeg = (grp < 2) ? grp * 13 : 26 + (grp - 2) * 12;
    const int sEnd = sBeg + ((grp < 2) ? 13 : 12);
    for (int s = sBeg; s < sEnd; ++s) {
        const size_t row = (size_t)g * 2500 + s * 50 + n;
        float v0, v1;
        if (FUSE) {
            const uint32_t hv = *(const uint32_t*)&HPb[row * 128 + c0];
            v0 = fmaxf(0.f, a1x * bf2f((unsigned short)(hv & 0xffff)) + b1x + hh0);
            v1 = fmaxf(0.f, a1y * bf2f((unsigned short)(hv >> 16)) + b1y + hh1);
        } else {
            v0 = HPf[row * 128 + c0];
            v1 = HPf[row * 128 + c1];
        }
        if (WRA3) {
            const uint32_t o = (uint32_t)f2bf(v0) | ((uint32_t)f2bf(v1) << 16);
            *(uint32_t*)&A3[row * 128 + c0] = o;
        }
        acc0 += v0; acc1 += v1;
    }
    red[tid * 2] = acc0; red[tid * 2 + 1] = acc1;
    __syncthreads();
    if (tid < 64) {
        float s0 = 0.f, s1 = 0.f;
        for (int gp = 0; gp < 4; ++gp) {
            s0 += red[(gp * 64 + tid) * 2];
            s1 += red[(gp * 64 + tid) * 2 + 1];
        }
        const uint32_t o = (uint32_t)f2bf(s0 * 0.02f) | ((uint32_t)f2bf(s1 * 0.02f) << 16);
        *(uint32_t*)&XS[(size_t)blk * 128 + tid * 2] = o;
    }
}

// ---------------------------------------------------------------------------
// pool (mean over n from XS) + MLP, fused: one block per graph.
// ---------------------------------------------------------------------------
__global__ __launch_bounds__(256)
void poolmlp_kernel(const unsigned short* __restrict__ XS,
                    const float* __restrict__ W1, const float* __restrict__ b1,
                    const float* __restrict__ W2, const float* __restrict__ b2,
                    float* __restrict__ out)
{
    __shared__ float red[256];
    __shared__ float hgs[128];
    __shared__ float hid[256];
    const int g = blockIdx.x, tid = threadIdx.x;
    const int c = tid & 127, h = tid >> 7;
    float s = 0.f;
    for (int n = h * 25; n < h * 25 + 25; ++n)
        s += bf2f(XS[(size_t)(g * 50 + n) * 128 + c]);
    red[tid] = s;
    __syncthreads();
    if (tid < 128) hgs[tid] = (red[tid] + red[128 + tid]) * 0.02f;
    __syncthreads();
    float a = b1[tid];
    for (int k = 0; k < 128; ++k) a += hgs[k] * W1[k * 256 + tid];
    hid[tid] = fmaxf(a, 0.f);
    __syncthreads();
    if (tid < 10) {
        float o = b2[tid];
        for (int k = 0; k < 256; ++k) o += hid[k] * W2[k * 10 + tid];
        out[g * 10 + tid] = o;
    }
}

extern "C" void kernel_launch(void* const* d_in, const int* in_sizes, int n_in,
                              void* d_out, int out_size, void* d_ws, size_t ws_size,
                              hipStream_t stream)
{
    const float* x0   = (const float*)d_in[0];
    const float* Wr   = (const float*)d_in[1];
    const float* Wn   = (const float*)d_in[2];
    const float* bb   = (const float*)d_in[3];
    const float* bng  = (const float*)d_in[4];
    const float* bnb  = (const float*)d_in[5];
    const float* Wsr  = (const float*)d_in[6];
    const float* Wsn  = (const float*)d_in[7];
    const float* bs   = (const float*)d_in[8];
    const float* bnsg = (const float*)d_in[9];
    const float* bnsb = (const float*)d_in[10];
    const float* fW1  = (const float*)d_in[11];
    const float* fb1  = (const float*)d_in[12];
    const float* fW2  = (const float*)d_in[13];
    const float* fb2  = (const float*)d_in[14];
    const int* ei     = (const int*)d_in[15];
    const int* oei    = (const int*)d_in[16];
    float* out        = (float*)d_out;

    char* w = (char*)d_ws;
    unsigned short* A3  = (unsigned short*)w; w += (size_t)TN * 128 * 2;
    unsigned short* H1  = (unsigned short*)w; w += (size_t)TN * 128 * 2;
    unsigned short* W3T = (unsigned short*)w; w += (size_t)8 * 65536 * 2;
    unsigned short* XS  = (unsigned short*)w; w += (size_t)NSUB * 128 * 2;
    unsigned short* H2  = (unsigned short*)w; w += (size_t)NSUB * 128 * 2;
    unsigned short* AdjS = (unsigned short*)w; w += (size_t)NSUB * 3200 * 2;
    unsigned short* AdjO = (unsigned short*)w; w += (size_t)GG * 3200 * 2 + 4096;
    float* stats        = (float*)w;          w += (size_t)65536 * 4;  // [4][2][32][256]

    setup_kernel<<<5568, 256, 0, stream>>>(Wr, Wn, Wsr, Wsn, W3T, ei, oei,
                                           AdjS, AdjO, stats);
    fusexsum_kernel<false, true><<<NSUB, 256, 0, stream>>>(
        x0, nullptr, nullptr, nullptr, nullptr, nullptr, nullptr, A3, XS);

    for (int i = 0; i < NL; ++i) {
        gconv_kernel<<<1632, 256, 0, stream>>>(A3, XS,
                                               W3T + (size_t)i * 65536,
                                               W3T + (size_t)(4 + i) * 65536,
                                               bb + i * 128, bs + i * 128,
                                               AdjS, AdjO, H1, H2,
                                               stats + (size_t)i * 16384);
        if (i < NL - 1)
            fusexsum_kernel<true, true><<<NSUB, 256, 0, stream>>>(
                H1, H2, stats + (size_t)i * 16384,
                bng + i * 128, bnb + i * 128, bnsg + i * 128, bnsb + i * 128,
                A3, XS);
        else
            fusexsum_kernel<true, false><<<NSUB, 256, 0, stream>>>(
                H1, H2, stats + (size_t)i * 16384,
                bng + i * 128, bnb + i * 128, bnsg + i * 128, bnsb + i * 128,
                A3, XS);
    }

    poolmlp_kernel<<<GG, 256, 0, stream>>>(XS, fW1, fb1, fW2, fb2, out);
}

// Round 15
// 361.622 us; speedup vs baseline: 1.5978x; 1.0081x over previous
//
#include <hip/hip_runtime.h>
#include <stdint.h>

#define D 128
#define TN 160000
#define NSUB 3200
#define GG 64
#define NL 4

typedef __bf16 bf16x8 __attribute__((ext_vector_type(8)));
typedef float f32x4 __attribute__((ext_vector_type(4)));
typedef unsigned int u32x4 __attribute__((ext_vector_type(4)));

__device__ __forceinline__ unsigned short f2bf(float v) {
    union { float f; uint32_t u; } c; c.f = v;
    uint32_t r = c.u + 0x7fffu + ((c.u >> 16) & 1u);
    return (unsigned short)(r >> 16);
}
__device__ __forceinline__ float bf2f(unsigned short h) {
    union { float f; uint32_t u; } c; c.u = ((uint32_t)h) << 16;
    return c.f;
}

__device__ __forceinline__ void gload16(const void* g, void* l) {
    __builtin_amdgcn_global_load_lds(
        (const __attribute__((address_space(1))) unsigned int*)g,
        (__attribute__((address_space(3))) unsigned int*)l, 16, 0, 0);
}

// ---------------------------------------------------------------------------
// Fused GraphConv, aggregation-as-MFMA (r11/r13 config; 2 blocks/CU is the
// L2-capacity sweet spot — r12 evidence). Block = 2 units x 256 cols.
// Grid 1632: blocks [0,32) = subgraph-conv (XS), [32,1632) = node-conv (A3).
// r15 changes: (1) Adj staged inside K-loop at t=4 (1024 granules, 4/thread
// uniform) -> barrier-1 drain is A+B0 only; tile 5 uses counted vmcnt(4)
// (oldest-first drain leaves the 4 newest = Adj in flight). (2) stage t+1
// issued BEFORE tile t's frag reads (different wave-private buffer).
// Main GEMM: 2-term precision y = x_hi*(Whi+Wlo); A staged once (XOR-swz);
// m-frags per unit {0,16,32,34}. Aggregation: agg = Adj x YnT via MFMA,
// H = Yr+agg+bias -> bf16; BN stats -> 32-way replicated atomics.
// ---------------------------------------------------------------------------
__global__ __launch_bounds__(256, 2)
void gconv_kernel(const unsigned short* __restrict__ A3,
                  const unsigned short* __restrict__ XS,
                  const unsigned short* __restrict__ Wt1,
                  const unsigned short* __restrict__ Wt2,
                  const float* __restrict__ bias1,
                  const float* __restrict__ bias2,
                  const unsigned short* __restrict__ AdjS,
                  const unsigned short* __restrict__ AdjO,
                  unsigned short* __restrict__ H1,
                  unsigned short* __restrict__ H2,
                  float* __restrict__ statsL)
{
    __shared__ __align__(16) char lds[74752];
    // 0..25600        A [100][128] sh (swz)   -> later YnT [128][136] sh (0..34816)
    // 25600..58368    B: 4 waves x 2 x 4096B ping-pong
    // 58368..74752    Adj [2][50][64] sh (swz) + slack (1024 granules)

    const int tid = threadIdx.x;
    const int blk = blockIdx.x;
    const bool big = blk >= 32;
    const int lb = big ? blk - 32 : blk;
    const unsigned short* Asrc = big ? A3 : XS;
    const unsigned short* Wt = big ? Wt1 : Wt2;
    const float* bias = big ? bias1 : bias2;
    const unsigned short* AdjG = (big ? AdjS : AdjO) + (size_t)lb * 6400;
    unsigned short* H = big ? H1 : H2;
    float* rep = statsL + (big ? 0 : 8192) + (size_t)(lb & 31) * 256;
    const int rowbase = lb * 100;

    const int lane = tid & 63, wv = tid >> 6;
    const int p = lane & 15, q = lane >> 4;
    const int wn0 = wv * 64;

    // ---- phase 1: stage A (1600 granules, swz) + B tile 0 only ----
#pragma unroll
    for (int i = 0; i < 6; ++i) {
        const int c = i * 256 + tid;
        const int r = c >> 4, g = c & 15;
        gload16(Asrc + (size_t)(rowbase + r) * 128 + ((g ^ (r & 7)) << 3),
                lds + ((i * 256 + (wv << 6)) << 4));
    }
    if (wv == 0) {
        const int c = 1536 + lane;
        const int r = c >> 4, g = c & 15;
        gload16(Asrc + (size_t)(rowbase + r) * 128 + ((g ^ (r & 7)) << 3),
                lds + (1536 << 4));
    }
    {
        char* dst = lds + 25600 + ((wv * 2 + 0) << 12);
#pragma unroll
        for (int j = 0; j < 4; ++j)
            gload16(Wt + (size_t)wn0 * 32 + (size_t)(j * 64 + lane) * 8,
                    dst + (j << 10));
    }

    f32x4 acc[8][4];
#pragma unroll
    for (int i = 0; i < 8; ++i)
#pragma unroll
        for (int j = 0; j < 4; ++j) acc[i][j] = (f32x4){0.f, 0.f, 0.f, 0.f};

    __syncthreads();   // barrier 1: A + B0 ready (Adj NOT in this drain)

    // ---- phase 2: K-loop, 8 tiles, ping-pong B, early stage-issue,
    //      Adj staged at t==4, counted vmcnt(4) at t==5 ----
    static const int FR[8] = {0, 16, 32, 34, 50, 66, 82, 84};
    const unsigned short* Ash = (const unsigned short*)lds;
#pragma unroll
    for (int t = 0; t < 8; ++t) {
        if (t > 0) {
            if (t == 5) asm volatile("s_waitcnt vmcnt(4)" ::: "memory");
            else        asm volatile("s_waitcnt vmcnt(0)" ::: "memory");
        }
        if (t < 7) {   // issue stage t+1 early (other ping-pong buffer)
            char* dst = lds + 25600 + ((wv * 2 + ((t + 1) & 1)) << 12);
#pragma unroll
            for (int j = 0; j < 4; ++j)
                gload16(Wt + ((size_t)(t + 1) << 13) + (size_t)wn0 * 32 +
                            (size_t)(j * 64 + lane) * 8,
                        dst + (j << 10));
        }
        if (t == 4) {  // issue Adj: 1024 granules, 4 per thread (uniform)
#pragma unroll
            for (int i = 0; i < 4; ++i) {
                const int c = i * 256 + tid;
                gload16(AdjG + (size_t)c * 8,
                        lds + 58368 + ((i * 256 + (wv << 6)) << 4));
            }
        }
        const unsigned short* Bw =
            (const unsigned short*)(lds + 25600 + ((wv * 2 + (t & 1)) << 12));
        bf16x8 bfr[4];
#pragma unroll
        for (int ni = 0; ni < 4; ++ni) {
            u32x4 raw = *(const u32x4*)&Bw[(ni * 16 + p) * 32 + q * 8];
            bfr[ni] = __builtin_bit_cast(bf16x8, raw);
        }
        const int gb = (t & 3) * 4 + q;
        __builtin_amdgcn_s_setprio(1);
#pragma unroll
        for (int mi = 0; mi < 8; ++mi) {
            const int rr = FR[mi] + p;
            u32x4 raw = *(const u32x4*)&Ash[rr * 128 + ((gb ^ (rr & 7)) << 3)];
            bf16x8 afr = __builtin_bit_cast(bf16x8, raw);
#pragma unroll
            for (int ni = 0; ni < 4; ++ni)
                acc[mi][ni] = __builtin_amdgcn_mfma_f32_16x16x32_bf16(afr, bfr[ni], acc[mi][ni], 0, 0, 0);
        }
        __builtin_amdgcn_s_setprio(0);
    }

    __syncthreads();   // barrier 2: all reads done + Adj drained; A+B reusable

    // ---- phase 3: waves 2,3 dump YnT (bf16, transposed); waves 0,1 zero pad
    static const int F4[4] = {0, 16, 32, 34};
    unsigned short* YnT = (unsigned short*)lds;
    if (wv >= 2) {
        const int cb = (wv - 2) * 64;
#pragma unroll
        for (int u = 0; u < 2; ++u)
#pragma unroll
            for (int fi = 0; fi < 4; ++fi) {
#pragma unroll
                for (int rp = 0; rp < 4; rp += 2) {
                    if (fi == 3 && (q * 4 + rp) < 14) continue;
                    const int jl = F4[fi] + q * 4 + rp;
#pragma unroll
                    for (int ni = 0; ni < 4; ++ni) {
                        const int c = cb + ni * 16 + p;
                        const uint32_t v =
                            (uint32_t)f2bf(acc[u * 4 + fi][ni][rp]) |
                            ((uint32_t)f2bf(acc[u * 4 + fi][ni][rp + 1]) << 16);
                        *(uint32_t*)&YnT[c * 136 + u * 64 + jl] = v;
                    }
                }
            }
    } else {
        const int c = wv * 64 + lane;   // 128 threads cover all cols
#pragma unroll
        for (int u = 0; u < 2; ++u)
#pragma unroll
            for (int k = 0; k < 7; ++k)
                *(uint32_t*)&YnT[c * 136 + u * 64 + 50 + k * 2] = 0;
    }
    __syncthreads();   // barrier 3

    // ---- phase 4: waves 0,1: agg = Adj x YnT (MFMA), H = Yr+agg+bias ----
    if (wv < 2) {
        const int cb = wv * 64;
        const unsigned short* AdjL = (const unsigned short*)(lds + 58368);
        float sm[4] = {0.f, 0.f, 0.f, 0.f}, sq[4] = {0.f, 0.f, 0.f, 0.f};
        float bv[4];
#pragma unroll
        for (int ni = 0; ni < 4; ++ni) bv[ni] = bias[cb + ni * 16 + p];
#pragma unroll
        for (int u = 0; u < 2; ++u) {
            f32x4 aacc[4][4];
#pragma unroll
            for (int i = 0; i < 4; ++i)
#pragma unroll
                for (int j = 0; j < 4; ++j) aacc[i][j] = (f32x4){0.f, 0.f, 0.f, 0.f};
#pragma unroll
            for (int ks = 0; ks < 2; ++ks) {
                bf16x8 afr[4], bfr2[4];
#pragma unroll
                for (int fi = 0; fi < 4; ++fi) {
                    const int m = F4[fi] + p;
                    const int gi = ks * 4 + q;
                    u32x4 raw = *(const u32x4*)&AdjL[(u * 50 + m) * 64 + ((gi ^ (m & 7)) << 3)];
                    afr[fi] = __builtin_bit_cast(bf16x8, raw);
                }
#pragma unroll
                for (int ni = 0; ni < 4; ++ni) {
                    u32x4 raw = *(const u32x4*)&YnT[(cb + ni * 16 + p) * 136 + u * 64 + ks * 32 + q * 8];
                    bfr2[ni] = __builtin_bit_cast(bf16x8, raw);
                }
#pragma unroll
                for (int fi = 0; fi < 4; ++fi)
#pragma unroll
                    for (int ni = 0; ni < 4; ++ni)
                        aacc[fi][ni] = __builtin_amdgcn_mfma_f32_16x16x32_bf16(afr[fi], bfr2[ni], aacc[fi][ni], 0, 0, 0);
            }
#pragma unroll
            for (int fi = 0; fi < 4; ++fi)
#pragma unroll
                for (int r = 0; r < 4; ++r) {
                    if (fi == 3 && (q * 4 + r) < 14) continue;
                    const int row = u * 50 + F4[fi] + q * 4 + r;
#pragma unroll
                    for (int ni = 0; ni < 4; ++ni) {
                        const int cc = cb + ni * 16 + p;
                        const float h = acc[u * 4 + fi][ni][r] + aacc[fi][ni][r] + bv[ni];
                        H[(size_t)(rowbase + row) * 128 + cc] = f2bf(h);
                        sm[ni] += h; sq[ni] += h * h;
                    }
                }
        }
#pragma unroll
        for (int ni = 0; ni < 4; ++ni) {
            atomicAdd(&rep[cb + ni * 16 + p], sm[ni]);
            atomicAdd(&rep[128 + cb + ni * 16 + p], sq[ni]);
        }
    }
}

// ---------------------------------------------------------------------------
// adj body (device): dense [50][64] multiplicity matrix in LDS, written bf16
// ([50][64] = 3200 shorts/unit, contiguous) with gconv granule swizzle.
// ---------------------------------------------------------------------------
__device__ __forceinline__ void adj_body(int u, const int* __restrict__ src,
                                         const int* __restrict__ dst,
                                         unsigned short* __restrict__ AdjG,
                                         int* cnt)
{
    const int t = threadIdx.x;
    for (int i = t; i < 3200; i += 256) cnt[i] = 0;
    __syncthreads();
    for (int e = t; e < 400; e += 256) {
        const int d = dst[u * 400 + e] - u * 50;
        const int s = src[u * 400 + e] - u * 50;
        atomicAdd(&cnt[d * 64 + s], 1);
    }
    __syncthreads();
    for (int i = t; i < 3200; i += 256) {
        const int m = i >> 6, j = i & 63;
        const float v = (float)cnt[i];
        const int pos = m * 64 + ((((j >> 3) ^ (m & 7)) << 3) | (j & 7));
        AdjG[(size_t)u * 3200 + pos] = f2bf(v);
    }
}

// ---------------------------------------------------------------------------
// setup: blocks [0,2048) build W3T; [2048,5248) AdjS; [5248,5312) AdjO;
// [5312,5568) zero the 4-layer stats (65536 floats).
// ---------------------------------------------------------------------------
__global__ __launch_bounds__(256)
void setup_kernel(const float* __restrict__ Wr, const float* __restrict__ Wn,
                  const float* __restrict__ Wsr, const float* __restrict__ Wsn,
                  unsigned short* __restrict__ W3T,
                  const int* __restrict__ ei, const int* __restrict__ oei,
                  unsigned short* __restrict__ AdjS,
                  unsigned short* __restrict__ AdjO,
                  float* __restrict__ stats)
{
    __shared__ int cnt[3200];
    const int b = blockIdx.x, t = threadIdx.x;
    if (b < 2048) {
        const int idx = b * 256 + t;
        const int m = idx >> 16;
        const int r = idx & 65535;
        const int bt = r >> 13;
        const int rr = r & 8191;
        const int n = rr >> 5, kloc = rr & 31;
        const int kg = (bt & 3) * 32 + kloc;
        const float* Wa = (m < 4) ? Wr + (size_t)m * 16384 : Wsr + (size_t)(m - 4) * 16384;
        const float* Wb = (m < 4) ? Wn + (size_t)m * 16384 : Wsn + (size_t)(m - 4) * 16384;
        const float w = (n < 128) ? Wa[kg * 128 + n] : Wb[kg * 128 + (n - 128)];
        const unsigned short hi = f2bf(w);
        W3T[idx] = (bt < 4) ? hi : f2bf(w - bf2f(hi));
    } else if (b < 5248) {
        adj_body(b - 2048, ei, ei + 1280000, AdjS, cnt);
    } else if (b < 5312) {
        adj_body(b - 5248, oei, oei + 25600, AdjO, cnt);
    } else {
        stats[(b - 5312) * 256 + t] = 0.f;
    }
}

// ---------------------------------------------------------------------------
// fusexsum: inline BN-param computation from this layer's stats slice, then
// x = relu(a1*h1 + c1 + a2*h2[node_idx] + c2) -> A3 bf16 (if WRA3), and
// subgraph-mean -> XS. Thread owns a channel pair (4B/lane); 4 row-groups.
// ---------------------------------------------------------------------------
template <bool FUSE, bool WRA3>
__global__ __launch_bounds__(256)
void fusexsum_kernel(const void* __restrict__ HPv,
                     const unsigned short* __restrict__ H2,
                     const float* __restrict__ statsL,
                     const float* __restrict__ bng, const float* __restrict__ bnb,
                     const float* __restrict__ bnsg, const float* __restrict__ bnsb,
                     unsigned short* __restrict__ A3,
                     unsigned short* __restrict__ XS)
{
    __shared__ float red[512];
    __shared__ float prmL[512];
    __shared__ float sN[256], sS[256];
    const unsigned short* HPb = (const unsigned short*)HPv;
    const float* HPf = (const float*)HPv;
    const int blk = blockIdx.x;          // g*50 + n
    const int g = blk / 50, n = blk - g * 50;
    const int tid = threadIdx.x;
    const int cp = tid & 63;             // channel pair -> channels 2cp, 2cp+1
    const int grp = tid >> 6;            // 0..3
    const int c0 = cp * 2, c1 = c0 + 1;

    if (FUSE) {
        float aN = 0.f, aS = 0.f;
#pragma unroll
        for (int r = 0; r < 32; ++r) {
            aN += statsL[r * 256 + tid];
            aS += statsL[8192 + r * 256 + tid];
        }
        sN[tid] = aN; sS[tid] = aS;
        __syncthreads();
        if (tid < 128) {
            const float mu = sN[tid] / (float)TN;
            const float var = sN[128 + tid] / (float)TN - mu * mu;
            const float a = bng[tid] / sqrtf(var + 1e-5f);
            prmL[tid] = a;
            prmL[128 + tid] = bnb[tid] - mu * a;
        } else {
            const int c = tid - 128;
            const float mu = sS[c] / (float)NSUB;
            const float var = sS[128 + c] / (float)NSUB - mu * mu;
            const float a = bnsg[c] / sqrtf(var + 1e-5f);
            prmL[256 + c] = a;
            prmL[384 + c] = bnsb[c] - mu * a;
        }
        __syncthreads();
    }

    float a1x = 0.f, b1x = 0.f, hh0 = 0.f, a1y = 0.f, b1y = 0.f, hh1 = 0.f;
    if (FUSE) {
        a1x = prmL[c0]; b1x = prmL[128 + c0];
        a1y = prmL[c1]; b1y = prmL[128 + c1];
        const uint32_t h2v = *(const uint32_t*)&H2[(size_t)blk * 128 + c0];
        hh0 = prmL[256 + c0] * bf2f((unsigned short)(h2v & 0xffff)) + prmL[384 + c0];
        hh1 = prmL[256 + c1] * bf2f((unsigned short)(h2v >> 16)) + prmL[384 + c1];
    }
    float acc0 = 0.f, acc1 = 0.f;
    const int sBeg = (grp < 2) ? grp * 13 : 26 + (grp - 2) * 12;
    const int sEnd = sBeg + ((grp < 2) ? 13 : 12);
    for (int s = sBeg; s < sEnd; ++s) {
        const size_t row = (size_t)g * 2500 + s * 50 + n;
        float v0, v1;
        if (FUSE) {
            const uint32_t hv = *(const uint32_t*)&HPb[row * 128 + c0];
            v0 = fmaxf(0.f, a1x * bf2f((unsigned short)(hv & 0xffff)) + b1x + hh0);
            v1 = fmaxf(0.f, a1y * bf2f((unsigned short)(hv >> 16)) + b1y + hh1);
        } else {
            v0 = HPf[row * 128 + c0];
            v1 = HPf[row * 128 + c1];
        }
        if (WRA3) {
            const uint32_t o = (uint32_t)f2bf(v0) | ((uint32_t)f2bf(v1) << 16);
            *(uint32_t*)&A3[row * 128 + c0] = o;
        }
        acc0 += v0; acc1 += v1;
    }
    red[tid * 2] = acc0; red[tid * 2 + 1] = acc1;
    __syncthreads();
    if (tid < 64) {
        float s0 = 0.f, s1 = 0.f;
        for (int gp = 0; gp < 4; ++gp) {
            s0 += red[(gp * 64 + tid) * 2];
            s1 += red[(gp * 64 + tid) * 2 + 1];
        }
        const uint32_t o = (uint32_t)f2bf(s0 * 0.02f) | ((uint32_t)f2bf(s1 * 0.02f) << 16);
        *(uint32_t*)&XS[(size_t)blk * 128 + tid * 2] = o;
    }
}

// ---------------------------------------------------------------------------
// pool (mean over n from XS) + MLP, fused: one block per graph.
// ---------------------------------------------------------------------------
__global__ __launch_bounds__(256)
void poolmlp_kernel(const unsigned short* __restrict__ XS,
                    const float* __restrict__ W1, const float* __restrict__ b1,
                    const float* __restrict__ W2, const float* __restrict__ b2,
                    float* __restrict__ out)
{
    __shared__ float red[256];
    __shared__ float hgs[128];
    __shared__ float hid[256];
    const int g = blockIdx.x, tid = threadIdx.x;
    const int c = tid & 127, h = tid >> 7;
    float s = 0.f;
    for (int n = h * 25; n < h * 25 + 25; ++n)
        s += bf2f(XS[(size_t)(g * 50 + n) * 128 + c]);
    red[tid] = s;
    __syncthreads();
    if (tid < 128) hgs[tid] = (red[tid] + red[128 + tid]) * 0.02f;
    __syncthreads();
    float a = b1[tid];
    for (int k = 0; k < 128; ++k) a += hgs[k] * W1[k * 256 + tid];
    hid[tid] = fmaxf(a, 0.f);
    __syncthreads();
    if (tid < 10) {
        float o = b2[tid];
        for (int k = 0; k < 256; ++k) o += hid[k] * W2[k * 10 + tid];
        out[g * 10 + tid] = o;
    }
}

extern "C" void kernel_launch(void* const* d_in, const int* in_sizes, int n_in,
                              void* d_out, int out_size, void* d_ws, size_t ws_size,
                              hipStream_t stream)
{
    const float* x0   = (const float*)d_in[0];
    const float* Wr   = (const float*)d_in[1];
    const float* Wn   = (const float*)d_in[2];
    const float* bb   = (const float*)d_in[3];
    const float* bng  = (const float*)d_in[4];
    const float* bnb  = (const float*)d_in[5];
    const float* Wsr  = (const float*)d_in[6];
    const float* Wsn  = (const float*)d_in[7];
    const float* bs   = (const float*)d_in[8];
    const float* bnsg = (const float*)d_in[9];
    const float* bnsb = (const float*)d_in[10];
    const float* fW1  = (const float*)d_in[11];
    const float* fb1  = (const float*)d_in[12];
    const float* fW2  = (const float*)d_in[13];
    const float* fb2  = (const float*)d_in[14];
    const int* ei     = (const int*)d_in[15];
    const int* oei    = (const int*)d_in[16];
    float* out        = (float*)d_out;

    char* w = (char*)d_ws;
    unsigned short* A3  = (unsigned short*)w; w += (size_t)TN * 128 * 2;
    unsigned short* H1  = (unsigned short*)w; w += (size_t)TN * 128 * 2;
    unsigned short* W3T = (unsigned short*)w; w += (size_t)8 * 65536 * 2;
    unsigned short* XS  = (unsigned short*)w; w += (size_t)NSUB * 128 * 2;
    unsigned short* H2  = (unsigned short*)w; w += (size_t)NSUB * 128 * 2;
    unsigned short* AdjS = (unsigned short*)w; w += (size_t)NSUB * 3200 * 2;
    unsigned short* AdjO = (unsigned short*)w; w += (size_t)GG * 3200 * 2 + 4096;
    float* stats        = (float*)w;          w += (size_t)65536 * 4;  // [4][2][32][256]

    setup_kernel<<<5568, 256, 0, stream>>>(Wr, Wn, Wsr, Wsn, W3T, ei, oei,
                                           AdjS, AdjO, stats);
    fusexsum_kernel<false, true><<<NSUB, 256, 0, stream>>>(
        x0, nullptr, nullptr, nullptr, nullptr, nullptr, nullptr, A3, XS);

    for (int i = 0; i < NL; ++i) {
        gconv_kernel<<<1632, 256, 0, stream>>>(A3, XS,
                                               W3T + (size_t)i * 65536,
                                               W3T + (size_t)(4 + i) * 65536,
                                               bb + i * 128, bs + i * 128,
                                               AdjS, AdjO, H1, H2,
                                               stats + (size_t)i * 16384);
        if (i < NL - 1)
            fusexsum_kernel<true, true><<<NSUB, 256, 0, stream>>>(
                H1, H2, stats + (size_t)i * 16384,
                bng + i * 128, bnb + i * 128, bnsg + i * 128, bnsb + i * 128,
                A3, XS);
        else
            fusexsum_kernel<true, false><<<NSUB, 256, 0, stream>>>(
                H1, H2, stats + (size_t)i * 16384,
                bng + i * 128, bnb + i * 128, bnsg + i * 128, bnsb + i * 128,
                A3, XS);
    }

    poolmlp_kernel<<<GG, 256, 0, stream>>>(XS, fW1, fb1, fW2, fb2, out);
}